// Round 7
// baseline (217.654 us; speedup 1.0000x reference)
//
#include <hip/hip_runtime.h>

// PagedKVCache: out = stack([k_cache.at[page,:,off].set(k_val), same for v])
//   k_cache/v_cache: [4096, 8, 16, 128] fp32 (256 MB each)
//   k_val/v_val:     [32, 512, 8, 128] fp32  (64 MB each)
//   slot_mapping:    [32, 512] int (16384 tokens)
//   out:             [2, 4096, 8, 16, 128] fp32 (512 MB)
//
// Gather formulation: map[slot] = overwriting token (else -1). One block per
// page writes every output float4 of that page exactly once (K and V).
// R7: SINGLE CHANGE vs R6 — all nontemporal load/store hints removed (plain
// accesses). The 6.7 TB/s reference fills use plain stores; nt bypasses L2
// write-combining and is the prime suspect for the uniform ~15% BW deficit.

#define NP   4096
#define NH   8
#define PG   16
#define HD   128
#define NTOK (32 * 512)
#define NSLOT (NP * PG)          // 65536
#define ROWF4 (HD / 4)           // 32
#define PAGEF4 (NH * PG * ROWF4) // 4096 float4 per page per cache half

static constexpr int CACHE_F4 = NP * PAGEF4; // 16,777,216 (fits int32)

typedef float f32x4 __attribute__((ext_vector_type(4)));

__global__ void pagedkv_build_map(const int* __restrict__ slots,
                                  int* __restrict__ map) {
    int t = blockIdx.x * blockDim.x + threadIdx.x;
    if (t < NTOK) map[slots[t]] = t;
}

__global__ __launch_bounds__(256) void pagedkv_gather(
        const f32x4* __restrict__ kc,
        const f32x4* __restrict__ vc,
        const f32x4* __restrict__ kv,
        const f32x4* __restrict__ vv,
        const int* __restrict__ map,
        f32x4* __restrict__ out) {
    __shared__ int toks[PG];
    __shared__ f32x4 lds[8 * 256];   // 32 KB: 8 tokens x 256 f4 (4 KB each)

    const int page = blockIdx.x;
    const int tid  = (int)threadIdx.x;
    if (tid < PG) toks[tid] = map[(page << 4) + tid];
    __syncthreads();

    int nneg = 0;
#pragma unroll
    for (int o = 0; o < PG; ++o) nneg += (toks[o] < 0) ? 1 : 0;

    const int pbase = page * PAGEF4;
    f32x4* __restrict__ outk = out;
    f32x4* __restrict__ outv = out + CACHE_F4;

    if (nneg == PG) {
        // ---- untouched page: pure streaming copy (1 KB/wave contiguous) ----
#pragma unroll
        for (int it = 0; it < PAGEF4 / 256; ++it) {
            const int gi = pbase + it * 256 + tid;
            outk[gi] = kc[gi];
            outv[gi] = vc[gi];
        }
    } else if (nneg == 0) {
        // ---- fully-overwritten page: LDS transpose, both sides contiguous --
        const int off = tid >> 5;        // 0..7 within chunk
        const int d4  = tid & 31;
#pragma unroll
        for (int half = 0; half < 2; ++half) {
            const f32x4* __restrict__ vals = half ? vv : kv;
            f32x4* __restrict__ dsth       = half ? outv : outk;
#pragma unroll
            for (int c = 0; c < 2; ++c) {          // offs c*8 .. c*8+7
#pragma unroll
                for (int o = 0; o < 8; ++o) {      // stage 8 tokens, 4 KB each
                    const int tok = toks[c * 8 + o];
                    lds[o * 256 + tid] = vals[tok * 256 + tid];
                }
                __syncthreads();
#pragma unroll
                for (int h = 0; h < 8; ++h) {      // drain 8 x 4 KB contiguous
                    dsth[pbase + (h << 9) + ((c * 8 + off) << 5) + d4] =
                        lds[off * 256 + h * 32 + d4];
                }
                __syncthreads();
            }
        }
    } else {
        // ---- mixed page: general per-lane source select ----
#pragma unroll
        for (int it = 0; it < PAGEF4 / 256; ++it) {
            const int i    = it * 256 + tid;
            const int d4   = i & 31;
            const int offm = (i >> 5) & 15;
            const int h    = i >> 9;
            const int tok  = toks[offm];
            const int gi   = pbase + i;
            const int s    = (tok * NH + h) * ROWF4 + d4;
            const f32x4* sk = (tok >= 0) ? (kv + s) : (kc + gi);
            const f32x4* sv = (tok >= 0) ? (vv + s) : (vc + gi);
            outk[gi] = *sk;
            outv[gi] = *sv;
        }
    }
}

extern "C" void kernel_launch(void* const* d_in, const int* in_sizes, int n_in,
                              void* d_out, int out_size, void* d_ws, size_t ws_size,
                              hipStream_t stream) {
    const f32x4* kc    = (const f32x4*)d_in[0];
    const f32x4* vc    = (const f32x4*)d_in[1];
    const f32x4* kv    = (const f32x4*)d_in[2];
    const f32x4* vv    = (const f32x4*)d_in[3];
    const int*   slots = (const int*)d_in[4];
    f32x4* out = (f32x4*)d_out;
    int*   map = (int*)d_ws;   // 65536 ints = 256 KB

    hipMemsetAsync(map, 0xFF, NSLOT * sizeof(int), stream);   // map[:] = -1
    pagedkv_build_map<<<NTOK / 256, 256, 0, stream>>>(slots, map);
    pagedkv_gather<<<NP, 256, 0, stream>>>(kc, vc, kv, vv, map, out);
}

// Round 8
// 200.226 us; speedup vs baseline: 1.0870x; 1.0870x over previous
//
#include <hip/hip_runtime.h>

// PagedKVCache: out = stack([k_cache.at[page,:,off].set(k_val), same for v])
//   k_cache/v_cache: [4096, 8, 16, 128] fp32 (256 MB each)
//   k_val/v_val:     [32, 512, 8, 128] fp32  (64 MB each)
//   slot_mapping:    [32, 512] int (16384 tokens)
//   out:             [2, 4096, 8, 16, 128] fp32 (512 MB)
//
// Gather formulation: map[slot] = overwriting token (else -1). One block per
// page writes every output float4 of that page exactly once (K and V).
// R8 vs R6: nt hints RESTORED (R7 proved them worth ~8%); LDS staging cut
// 32->16 KB (8 blocks/CU instead of 4 -> 2x resident waves); copy path
// explicitly batches 8 loads into registers before 8 stores (guaranteed MLP).

#define NP   4096
#define NH   8
#define PG   16
#define HD   128
#define NTOK (32 * 512)
#define NSLOT (NP * PG)          // 65536
#define ROWF4 (HD / 4)           // 32
#define PAGEF4 (NH * PG * ROWF4) // 4096 float4 per page per cache half

static constexpr int CACHE_F4 = NP * PAGEF4; // 16,777,216 (fits int32)

typedef float f32x4 __attribute__((ext_vector_type(4)));

__global__ void pagedkv_build_map(const int* __restrict__ slots,
                                  int* __restrict__ map) {
    int t = blockIdx.x * blockDim.x + threadIdx.x;
    if (t < NTOK) map[slots[t]] = t;
}

__global__ __launch_bounds__(256) void pagedkv_gather(
        const f32x4* __restrict__ kc,
        const f32x4* __restrict__ vc,
        const f32x4* __restrict__ kv,
        const f32x4* __restrict__ vv,
        const int* __restrict__ map,
        f32x4* __restrict__ out) {
    __shared__ int toks[PG];
    __shared__ f32x4 lds[4 * 256];   // 16 KB: 4 tokens x 256 f4 (4 KB each)

    const int page = blockIdx.x;
    const int tid  = (int)threadIdx.x;
    if (tid < PG) toks[tid] = map[(page << 4) + tid];
    __syncthreads();

    int nneg = 0;
#pragma unroll
    for (int o = 0; o < PG; ++o) nneg += (toks[o] < 0) ? 1 : 0;

    const int pbase = page * PAGEF4;
    f32x4* __restrict__ outk = out;
    f32x4* __restrict__ outv = out + CACHE_F4;

    if (nneg == PG) {
        // ---- untouched page: streaming copy, 8 loads in flight per batch ---
#pragma unroll
        for (int g = 0; g < 4; ++g) {
            f32x4 rk[4], rv[4];
#pragma unroll
            for (int j = 0; j < 4; ++j) {
                const int gi = pbase + (g * 4 + j) * 256 + tid;
                rk[j] = __builtin_nontemporal_load(kc + gi);
                rv[j] = __builtin_nontemporal_load(vc + gi);
            }
#pragma unroll
            for (int j = 0; j < 4; ++j) {
                const int gi = pbase + (g * 4 + j) * 256 + tid;
                __builtin_nontemporal_store(rk[j], outk + gi);
                __builtin_nontemporal_store(rv[j], outv + gi);
            }
        }
    } else if (nneg == 0) {
        // ---- fully-overwritten page: LDS transpose, both sides contiguous --
        // Stage 4 tokens x 4 KB (contiguous reads), drain contiguous per-h.
#pragma unroll
        for (int half = 0; half < 2; ++half) {
            const f32x4* __restrict__ vals = half ? vv : kv;
            f32x4* __restrict__ dsth       = half ? outv : outk;
#pragma unroll
            for (int c = 0; c < 4; ++c) {          // offs c*4 .. c*4+3
#pragma unroll
                for (int o = 0; o < 4; ++o) {      // stage 4 tokens
                    const int tok = toks[c * 4 + o];
                    lds[o * 256 + tid] =
                        __builtin_nontemporal_load(vals + tok * 256 + tid);
                }
                __syncthreads();
#pragma unroll
                for (int j = 0; j < 4; ++j) {      // drain 1024 f4
                    const int u    = j * 256 + tid;   // [0,1024)
                    const int d4   = u & 31;
                    const int off4 = (u >> 5) & 3;
                    const int h    = u >> 7;
                    __builtin_nontemporal_store(
                        lds[off4 * 256 + h * 32 + d4],
                        dsth + pbase + (h << 9) + ((c * 4 + off4) << 5) + d4);
                }
                __syncthreads();
            }
        }
    } else {
        // ---- mixed page: general per-lane source select ----
#pragma unroll
        for (int it = 0; it < PAGEF4 / 256; ++it) {
            const int i    = it * 256 + tid;
            const int d4   = i & 31;
            const int offm = (i >> 5) & 15;
            const int h    = i >> 9;
            const int tok  = toks[offm];
            const int gi   = pbase + i;
            const int s    = (tok * NH + h) * ROWF4 + d4;
            const f32x4* sk = (tok >= 0) ? (kv + s) : (kc + gi);
            const f32x4* sv = (tok >= 0) ? (vv + s) : (vc + gi);
            f32x4 k = __builtin_nontemporal_load(sk);
            f32x4 v = __builtin_nontemporal_load(sv);
            __builtin_nontemporal_store(k, outk + gi);
            __builtin_nontemporal_store(v, outv + gi);
        }
    }
}

extern "C" void kernel_launch(void* const* d_in, const int* in_sizes, int n_in,
                              void* d_out, int out_size, void* d_ws, size_t ws_size,
                              hipStream_t stream) {
    const f32x4* kc    = (const f32x4*)d_in[0];
    const f32x4* vc    = (const f32x4*)d_in[1];
    const f32x4* kv    = (const f32x4*)d_in[2];
    const f32x4* vv    = (const f32x4*)d_in[3];
    const int*   slots = (const int*)d_in[4];
    f32x4* out = (f32x4*)d_out;
    int*   map = (int*)d_ws;   // 65536 ints = 256 KB

    hipMemsetAsync(map, 0xFF, NSLOT * sizeof(int), stream);   // map[:] = -1
    pagedkv_build_map<<<NTOK / 256, 256, 0, stream>>>(slots, map);
    pagedkv_gather<<<NP, 256, 0, stream>>>(kc, vc, kv, vv, map, out);
}